// Round 1
// baseline (336.602 us; speedup 1.0000x reference)
//
#include <hip/hip_runtime.h>
#include <hip/hip_bf16.h>
#include <math.h>

#define Bb 4
#define Ss 4096
#define Dd 1024
#define Aa 128

typedef __attribute__((ext_vector_type(4))) float f32x4;
typedef __attribute__((ext_vector_type(8))) short bf16x8;

static __device__ __forceinline__ unsigned short f2bf(float f) {
  union { float f; unsigned u; } v; v.f = f;
  unsigned r = v.u + 0x7fffu + ((v.u >> 16) & 1u);
  return (unsigned short)(r >> 16);
}

// ---------------------------------------------------------------------------
// Kernel 0: convert Wq/Wk/Wv (fp32 [D][A]) -> bf16 transposed Wt[w][n][k]
// ---------------------------------------------------------------------------
__global__ void wconv_kernel(const float* __restrict__ Wq, const float* __restrict__ Wk,
                             const float* __restrict__ Wv, unsigned short* __restrict__ Wt) {
  int w = blockIdx.y;
  const float* Wsrc = (w == 0) ? Wq : ((w == 1) ? Wk : Wv);
  int t = blockIdx.x * blockDim.x + threadIdx.x;
  if (t >= Dd * Aa) return;
  int k = t / Aa, n = t % Aa;
  Wt[(size_t)w * Aa * Dd + (size_t)n * Dd + k] = f2bf(Wsrc[t]);
}

// ---------------------------------------------------------------------------
// Kernel 1: QKV projection GEMM.  X [16384][1024] fp32  x  Wt[w] [128][1024] bf16
//   -> Qb (scaled by 1/sqrt(128)), Kb  as [16384][128] bf16
//   -> Vt as [B][128][4096] bf16 (transposed for the PV step)
// BM=128, BN=128, BK=64, 256 threads = 4 waves, each wave 64x64.
// ---------------------------------------------------------------------------
__global__ __launch_bounds__(256) void qkv_kernel(const float* __restrict__ X,
    const unsigned short* __restrict__ Wt,
    unsigned short* __restrict__ Qb, unsigned short* __restrict__ Kb,
    unsigned short* __restrict__ Vt) {
  __shared__ unsigned short As[128][72];   // [m][k], +8 pad
  __shared__ unsigned short Bs[128][72];   // [n][k], +8 pad
  const int tid = threadIdx.x;
  const int lane = tid & 63;
  const int wid = tid >> 6;
  const int wr = wid >> 1, wc = wid & 1;
  const int g = lane >> 4, r16 = lane & 15;
  const int mblk = blockIdx.x;
  const int w = blockIdx.y;
  const unsigned short* Wsrc = Wt + (size_t)w * Aa * Dd;

  f32x4 acc[4][4];
  const f32x4 fz = {0.f, 0.f, 0.f, 0.f};
#pragma unroll
  for (int mi = 0; mi < 4; ++mi)
#pragma unroll
    for (int nj = 0; nj < 4; ++nj) acc[mi][nj] = fz;

  for (int kb = 0; kb < Dd; kb += 64) {
    // stage A tile 128x64 (fp32 -> bf16)
#pragma unroll
    for (int i = 0; i < 8; ++i) {
      int linear = tid + i * 256;        // float4 units, 2048 total
      int r = linear >> 4;
      int c = (linear & 15) << 2;
      const float4 v = *reinterpret_cast<const float4*>(
          &X[(size_t)(mblk * 128 + r) * Dd + kb + c]);
      ushort4 u;
      u.x = f2bf(v.x); u.y = f2bf(v.y); u.z = f2bf(v.z); u.w = f2bf(v.w);
      *reinterpret_cast<ushort4*>(&As[r][c]) = u;
    }
    // stage B tile: Bs[n][k] from Wt (already transposed bf16)
#pragma unroll
    for (int i = 0; i < 4; ++i) {
      int linear = tid + i * 256;        // 8-bf16 chunks, 1024 total
      int n = linear >> 3;
      int c = (linear & 7) << 3;
      *reinterpret_cast<int4*>(&Bs[n][c]) =
          *reinterpret_cast<const int4*>(&Wsrc[(size_t)n * Dd + kb + c]);
    }
    __syncthreads();
#pragma unroll
    for (int ks = 0; ks < 2; ++ks) {
      bf16x8 a[4], b[4];
#pragma unroll
      for (int mi = 0; mi < 4; ++mi)
        a[mi] = *reinterpret_cast<const bf16x8*>(&As[wr * 64 + mi * 16 + r16][ks * 32 + g * 8]);
#pragma unroll
      for (int nj = 0; nj < 4; ++nj)
        b[nj] = *reinterpret_cast<const bf16x8*>(&Bs[wc * 64 + nj * 16 + r16][ks * 32 + g * 8]);
#pragma unroll
      for (int mi = 0; mi < 4; ++mi)
#pragma unroll
        for (int nj = 0; nj < 4; ++nj)
          acc[mi][nj] = __builtin_amdgcn_mfma_f32_16x16x32_bf16(a[mi], b[nj], acc[mi][nj], 0, 0, 0);
    }
    __syncthreads();
  }

  const float qscale = 0.08838834764831845f;  // 1/sqrt(128)
#pragma unroll
  for (int mi = 0; mi < 4; ++mi) {
#pragma unroll
    for (int nj = 0; nj < 4; ++nj) {
#pragma unroll
      for (int i = 0; i < 4; ++i) {
        int m = wr * 64 + mi * 16 + g * 4 + i;   // C/D: row=(lane>>4)*4+reg
        int n = wc * 64 + nj * 16 + r16;         //      col=lane&15
        size_t grow = (size_t)mblk * 128 + m;
        float val = acc[mi][nj][i];
        if (w == 0) {
          Qb[grow * Aa + n] = f2bf(val * qscale);
        } else if (w == 1) {
          Kb[grow * Aa + n] = f2bf(val);
        } else {
          size_t bb = grow >> 12;
          size_t s = grow & 4095;
          Vt[(bb * Aa + n) * Ss + s] = f2bf(val);
        }
      }
    }
  }
}

// ---------------------------------------------------------------------------
// Kernel 2: causal flash attention.
// Block = 256 threads = 4 waves; each wave owns 16 q rows (block: 64 rows).
// KV tiles of 32. Online softmax. bf16 MFMA for QK^T and PV.
// ---------------------------------------------------------------------------
__global__ __launch_bounds__(256) void attn_kernel(const unsigned short* __restrict__ Qb,
    const unsigned short* __restrict__ Kb, const unsigned short* __restrict__ Vt,
    float* __restrict__ out) {
  __shared__ unsigned short Ks[32][136];    // [kv][d], +8 pad
  __shared__ unsigned short Vs[128][40];    // [d][kv], +8 pad
  __shared__ unsigned short Ps[4][16][40];  // per-wave P tile [qrow][kv]
  const int tid = threadIdx.x;
  const int lane = tid & 63;
  const int wid = tid >> 6;
  const int g = lane >> 4, c16 = lane & 15;
  const int b = blockIdx.y;
  const int qb = blockIdx.x * 64;
  const int qbase = qb + wid * 16;

  // Q fragments for this wave's 16 rows (A-operand: row=lane&15, k=8*(lane>>4)+i)
  const unsigned short* Qp = Qb + ((size_t)b * Ss + qbase) * Aa;
  bf16x8 qf[4];
#pragma unroll
  for (int kk = 0; kk < 4; ++kk)
    qf[kk] = *reinterpret_cast<const bf16x8*>(&Qp[(size_t)c16 * Aa + kk * 32 + g * 8]);

  const f32x4 fz = {0.f, 0.f, 0.f, 0.f};
  f32x4 o[8];
#pragma unroll
  for (int nt = 0; nt < 8; ++nt) o[nt] = fz;
  float mrun[4], lrun[4];
#pragma unroll
  for (int i = 0; i < 4; ++i) { mrun[i] = -INFINITY; lrun[i] = 0.f; }

  const int nkv = qb / 32 + 2;   // cover kv < qb + 64
  for (int it = 0; it < nkv; ++it) {
    const int kv0 = it * 32;
    // stage K tile [32][128]
#pragma unroll
    for (int i = 0; i < 2; ++i) {
      int idx = tid + i * 256;
      int r = idx >> 4;
      int c = (idx & 15) << 3;
      *reinterpret_cast<int4*>(&Ks[r][c]) =
          *reinterpret_cast<const int4*>(&Kb[((size_t)b * Ss + kv0 + r) * Aa + c]);
    }
    // stage V^T tile [128][32]
#pragma unroll
    for (int i = 0; i < 2; ++i) {
      int idx = tid + i * 256;
      int r = idx >> 2;
      int c = (idx & 3) << 3;
      *reinterpret_cast<int4*>(&Vs[r][c]) =
          *reinterpret_cast<const int4*>(&Vt[((size_t)b * Aa + r) * Ss + kv0 + c]);
    }
    __syncthreads();

    // S = Q K^T for 16x32 tile (2 n-tiles x 4 k-frags)
    f32x4 s[2];
    s[0] = fz; s[1] = fz;
#pragma unroll
    for (int nt = 0; nt < 2; ++nt)
#pragma unroll
      for (int kk = 0; kk < 4; ++kk) {
        bf16x8 kf = *reinterpret_cast<const bf16x8*>(&Ks[nt * 16 + c16][kk * 32 + g * 8]);
        s[nt] = __builtin_amdgcn_mfma_f32_16x16x32_bf16(qf[kk], kf, s[nt], 0, 0, 0);
      }

    // online softmax; lane holds rows m=4g+i, cols nt*16+c16
    float e0[4], e1[4], sc[4];
#pragma unroll
    for (int i = 0; i < 4; ++i) {
      int qrow = qbase + g * 4 + i;
      float s0 = (kv0 + c16 > qrow) ? -INFINITY : s[0][i];
      float s1 = (kv0 + 16 + c16 > qrow) ? -INFINITY : s[1][i];
      float pm = fmaxf(s0, s1);
#pragma unroll
      for (int msk = 1; msk <= 8; msk <<= 1)
        pm = fmaxf(pm, __shfl_xor(pm, msk, 64));
      float mnew = fmaxf(mrun[i], pm);
      float scale, p0, p1;
      if (mnew == -INFINITY) { scale = 1.f; p0 = 0.f; p1 = 0.f; }
      else {
        scale = __expf(mrun[i] - mnew);
        p0 = __expf(s0 - mnew);
        p1 = __expf(s1 - mnew);
      }
      float rs = p0 + p1;
#pragma unroll
      for (int msk = 1; msk <= 8; msk <<= 1)
        rs += __shfl_xor(rs, msk, 64);
      lrun[i] = lrun[i] * scale + rs;
      mrun[i] = mnew;
      sc[i] = scale; e0[i] = p0; e1[i] = p1;
    }
    // rescale O accumulators
#pragma unroll
    for (int nt = 0; nt < 8; ++nt)
#pragma unroll
      for (int i = 0; i < 4; ++i) o[nt][i] *= sc[i];

    // P -> LDS (wave-local) to get MFMA A-layout, then PV
#pragma unroll
    for (int i = 0; i < 4; ++i) {
      Ps[wid][g * 4 + i][c16] = f2bf(e0[i]);
      Ps[wid][g * 4 + i][16 + c16] = f2bf(e1[i]);
    }
    bf16x8 pf = *reinterpret_cast<const bf16x8*>(&Ps[wid][c16][g * 8]);
#pragma unroll
    for (int nt = 0; nt < 8; ++nt) {
      bf16x8 vf = *reinterpret_cast<const bf16x8*>(&Vs[nt * 16 + c16][g * 8]);
      o[nt] = __builtin_amdgcn_mfma_f32_16x16x32_bf16(pf, vf, o[nt], 0, 0, 0);
    }
    __syncthreads();
  }

  // epilogue: normalize, round to 4 decimals, store fp32
#pragma unroll
  for (int nt = 0; nt < 8; ++nt)
#pragma unroll
    for (int i = 0; i < 4; ++i) {
      int qrow = qbase + g * 4 + i;
      float val = o[nt][i] / lrun[i];
      val = rintf(val * 1e4f) * 1e-4f;
      out[((size_t)b * Ss + qrow) * Aa + nt * 16 + c16] = val;
    }
}

// ---------------------------------------------------------------------------
extern "C" void kernel_launch(void* const* d_in, const int* in_sizes, int n_in,
                              void* d_out, int out_size, void* d_ws, size_t ws_size,
                              hipStream_t stream) {
  const float* X  = (const float*)d_in[0];
  const float* Wq = (const float*)d_in[1];
  const float* Wk = (const float*)d_in[2];
  const float* Wv = (const float*)d_in[3];
  float* out = (float*)d_out;

  unsigned char* ws = (unsigned char*)d_ws;
  unsigned short* Qb = (unsigned short*)(ws);                 // 16384*128 bf16 = 4 MB
  unsigned short* Kb = (unsigned short*)(ws + 4194304);       // 4 MB
  unsigned short* Vt = (unsigned short*)(ws + 8388608);       // [B][128][4096] = 4 MB
  unsigned short* Wt = (unsigned short*)(ws + 12582912);      // [3][128][1024] = 768 KB

  hipLaunchKernelGGL(wconv_kernel, dim3(512, 3), dim3(256), 0, stream, Wq, Wk, Wv, Wt);
  hipLaunchKernelGGL(qkv_kernel, dim3(128, 3), dim3(256), 0, stream, X, Wt, Qb, Kb, Vt);
  hipLaunchKernelGGL(attn_kernel, dim3(64, 4), dim3(256), 0, stream, Qb, Kb, Vt, out);
}

// Round 2
// 326.287 us; speedup vs baseline: 1.0316x; 1.0316x over previous
//
#include <hip/hip_runtime.h>
#include <hip/hip_bf16.h>
#include <math.h>

#define Bb 4
#define Ss 4096
#define Dd 1024
#define Aa 128

typedef __attribute__((ext_vector_type(4))) float f32x4;
typedef __attribute__((ext_vector_type(8))) short bf16x8;

static __device__ __forceinline__ unsigned short f2bf(float f) {
  union { float f; unsigned u; } v; v.f = f;
  unsigned r = v.u + 0x7fffu + ((v.u >> 16) & 1u);
  return (unsigned short)(r >> 16);
}

// ---------------------------------------------------------------------------
// Kernel 0: convert Wq/Wk/Wv (fp32 [D][A]) -> bf16 transposed Wt[w][n][k]
// ---------------------------------------------------------------------------
__global__ void wconv_kernel(const float* __restrict__ Wq, const float* __restrict__ Wk,
                             const float* __restrict__ Wv, unsigned short* __restrict__ Wt) {
  int w = blockIdx.y;
  const float* Wsrc = (w == 0) ? Wq : ((w == 1) ? Wk : Wv);
  int t = blockIdx.x * blockDim.x + threadIdx.x;
  if (t >= Dd * Aa) return;
  int k = t / Aa, n = t % Aa;
  Wt[(size_t)w * Aa * Dd + (size_t)n * Dd + k] = f2bf(Wsrc[t]);
}

// ---------------------------------------------------------------------------
// Kernel 1: QKV projection GEMM.  X [16384][1024] fp32  x  Wt[w] [128][1024] bf16
//   -> Qb (scaled by 1/sqrt(128)), Kb  as [16384][128] bf16
//   -> Vt as [B][128][4096] bf16 (transposed for the PV step)
// BM=128, BN=128, BK=64, 256 threads = 4 waves, each wave 64x64.
// ---------------------------------------------------------------------------
__global__ __launch_bounds__(256) void qkv_kernel(const float* __restrict__ X,
    const unsigned short* __restrict__ Wt,
    unsigned short* __restrict__ Qb, unsigned short* __restrict__ Kb,
    unsigned short* __restrict__ Vt) {
  __shared__ unsigned short As[128][72];   // [m][k], +8 pad
  __shared__ unsigned short Bs[128][72];   // [n][k], +8 pad
  const int tid = threadIdx.x;
  const int lane = tid & 63;
  const int wid = tid >> 6;
  const int wr = wid >> 1, wc = wid & 1;
  const int g = lane >> 4, r16 = lane & 15;
  const int mblk = blockIdx.x;
  const int w = blockIdx.y;
  const unsigned short* Wsrc = Wt + (size_t)w * Aa * Dd;

  f32x4 acc[4][4];
  const f32x4 fz = {0.f, 0.f, 0.f, 0.f};
#pragma unroll
  for (int mi = 0; mi < 4; ++mi)
#pragma unroll
    for (int nj = 0; nj < 4; ++nj) acc[mi][nj] = fz;

  for (int kb = 0; kb < Dd; kb += 64) {
    // stage A tile 128x64 (fp32 -> bf16)
#pragma unroll
    for (int i = 0; i < 8; ++i) {
      int linear = tid + i * 256;        // float4 units, 2048 total
      int r = linear >> 4;
      int c = (linear & 15) << 2;
      const float4 v = *reinterpret_cast<const float4*>(
          &X[(size_t)(mblk * 128 + r) * Dd + kb + c]);
      ushort4 u;
      u.x = f2bf(v.x); u.y = f2bf(v.y); u.z = f2bf(v.z); u.w = f2bf(v.w);
      *reinterpret_cast<ushort4*>(&As[r][c]) = u;
    }
    // stage B tile: Bs[n][k] from Wt (already transposed bf16)
#pragma unroll
    for (int i = 0; i < 4; ++i) {
      int linear = tid + i * 256;        // 8-bf16 chunks, 1024 total
      int n = linear >> 3;
      int c = (linear & 7) << 3;
      *reinterpret_cast<int4*>(&Bs[n][c]) =
          *reinterpret_cast<const int4*>(&Wsrc[(size_t)n * Dd + kb + c]);
    }
    __syncthreads();
#pragma unroll
    for (int ks = 0; ks < 2; ++ks) {
      bf16x8 a[4], b[4];
#pragma unroll
      for (int mi = 0; mi < 4; ++mi)
        a[mi] = *reinterpret_cast<const bf16x8*>(&As[wr * 64 + mi * 16 + r16][ks * 32 + g * 8]);
#pragma unroll
      for (int nj = 0; nj < 4; ++nj)
        b[nj] = *reinterpret_cast<const bf16x8*>(&Bs[wc * 64 + nj * 16 + r16][ks * 32 + g * 8]);
#pragma unroll
      for (int mi = 0; mi < 4; ++mi)
#pragma unroll
        for (int nj = 0; nj < 4; ++nj)
          acc[mi][nj] = __builtin_amdgcn_mfma_f32_16x16x32_bf16(a[mi], b[nj], acc[mi][nj], 0, 0, 0);
    }
    __syncthreads();
  }

  const float qscale = 0.08838834764831845f;  // 1/sqrt(128)
#pragma unroll
  for (int mi = 0; mi < 4; ++mi) {
#pragma unroll
    for (int nj = 0; nj < 4; ++nj) {
#pragma unroll
      for (int i = 0; i < 4; ++i) {
        int m = wr * 64 + mi * 16 + g * 4 + i;   // C/D: row=(lane>>4)*4+reg
        int n = wc * 64 + nj * 16 + r16;         //      col=lane&15
        size_t grow = (size_t)mblk * 128 + m;
        float val = acc[mi][nj][i];
        if (w == 0) {
          Qb[grow * Aa + n] = f2bf(val * qscale);
        } else if (w == 1) {
          Kb[grow * Aa + n] = f2bf(val);
        } else {
          size_t bb = grow >> 12;
          size_t s = grow & 4095;
          Vt[(bb * Aa + n) * Ss + s] = f2bf(val);
        }
      }
    }
  }
}

// ---------------------------------------------------------------------------
// Kernel 2: causal flash attention — ONE WAVE PER BLOCK, barrier-free.
// Block = 64 threads; block t owns q rows [16t, 16t+16), iterates kv tiles of 32.
// K/V fragments load directly global->VGPR (L2-resident). P transposes through
// 1.3 KB wave-local LDS (same-wave DS ordering, no barrier). 1024 blocks total.
// ---------------------------------------------------------------------------
__global__ __launch_bounds__(64) void attn_kernel(const unsigned short* __restrict__ Qb,
    const unsigned short* __restrict__ Kb, const unsigned short* __restrict__ Vt,
    float* __restrict__ out) {
  __shared__ unsigned short Ps[16][40];     // wave-local P transpose buffer
  const int lane = threadIdx.x;
  const int g = lane >> 4, c16 = lane & 15;
  const int t = 255 - blockIdx.x;           // longest blocks first
  const int b = blockIdx.y;
  const int qbase = t * 16;

  // Q fragments: A-operand, row=lane&15, k=8*(lane>>4)+i  (pre-scaled by 1/sqrt(A))
  const unsigned short* Qp = Qb + ((size_t)b * Ss + qbase) * Aa;
  bf16x8 qf[4];
#pragma unroll
  for (int kk = 0; kk < 4; ++kk)
    qf[kk] = *reinterpret_cast<const bf16x8*>(&Qp[(size_t)c16 * Aa + kk * 32 + g * 8]);

  const unsigned short* Kbase = Kb + (size_t)b * Ss * Aa;
  const unsigned short* Vbase = Vt + (size_t)b * Aa * Ss;

  const f32x4 fz = {0.f, 0.f, 0.f, 0.f};
  f32x4 o[8];
#pragma unroll
  for (int nt = 0; nt < 8; ++nt) o[nt] = fz;
  float mrun[4], lrun[4];
#pragma unroll
  for (int i = 0; i < 4; ++i) { mrun[i] = -INFINITY; lrun[i] = 0.f; }

  const int nkv = (qbase + 47) >> 5;        // cover kv <= qbase+15
#pragma unroll 2
  for (int it = 0; it < nkv; ++it) {
    const int kv0 = it * 32;
    // K fragments: B-operand rows = kv, k = d. 16B loads, L2-resident.
    bf16x8 kf[2][4];
#pragma unroll
    for (int nt = 0; nt < 2; ++nt)
#pragma unroll
      for (int kk = 0; kk < 4; ++kk)
        kf[nt][kk] = *reinterpret_cast<const bf16x8*>(
            &Kbase[(size_t)(kv0 + nt * 16 + c16) * Aa + kk * 32 + g * 8]);
    // V fragments: B-operand rows = d (from Vt), k = kv. Issue early.
    bf16x8 vf[8];
#pragma unroll
    for (int nt = 0; nt < 8; ++nt)
      vf[nt] = *reinterpret_cast<const bf16x8*>(
          &Vbase[(size_t)(nt * 16 + c16) * Ss + kv0 + g * 8]);

    // S = Q K^T (16x32): two 16x16 n-tiles, K=128 via 4 chained MFMA each
    f32x4 s0 = fz, s1 = fz;
#pragma unroll
    for (int kk = 0; kk < 4; ++kk)
      s0 = __builtin_amdgcn_mfma_f32_16x16x32_bf16(qf[kk], kf[0][kk], s0, 0, 0, 0);
#pragma unroll
    for (int kk = 0; kk < 4; ++kk)
      s1 = __builtin_amdgcn_mfma_f32_16x16x32_bf16(qf[kk], kf[1][kk], s1, 0, 0, 0);

    // online softmax; lane holds rows 4g+i, cols {c16, 16+c16}
    const bool need_mask = (kv0 + 31 > qbase);   // wave-uniform
    float e0[4], e1[4], sc[4];
#pragma unroll
    for (int i = 0; i < 4; ++i) {
      float v0 = s0[i], v1 = s1[i];
      if (need_mask) {
        int qrow = qbase + g * 4 + i;
        if (kv0 + c16 > qrow) v0 = -INFINITY;
        if (kv0 + 16 + c16 > qrow) v1 = -INFINITY;
      }
      float pm = fmaxf(v0, v1);
#pragma unroll
      for (int msk = 1; msk <= 8; msk <<= 1)
        pm = fmaxf(pm, __shfl_xor(pm, msk));
      float mnew = fmaxf(mrun[i], pm);          // always finite
      float p0 = __expf(v0 - mnew);             // -inf -> 0
      float p1 = __expf(v1 - mnew);
      sc[i] = __expf(mrun[i] - mnew);
      float rs = p0 + p1;
#pragma unroll
      for (int msk = 1; msk <= 8; msk <<= 1)
        rs += __shfl_xor(rs, msk);
      lrun[i] = lrun[i] * sc[i] + rs;
      mrun[i] = mnew;
      e0[i] = p0; e1[i] = p1;
    }
    // rescale O
#pragma unroll
    for (int nt = 0; nt < 8; ++nt)
#pragma unroll
      for (int i = 0; i < 4; ++i) o[nt][i] *= sc[i];

    // P -> LDS transpose (wave-local, same-wave DS ordering; no barrier)
#pragma unroll
    for (int i = 0; i < 4; ++i) {
      Ps[g * 4 + i][c16] = f2bf(e0[i]);
      Ps[g * 4 + i][16 + c16] = f2bf(e1[i]);
    }
    bf16x8 pf = *reinterpret_cast<const bf16x8*>(&Ps[c16][g * 8]);
#pragma unroll
    for (int nt = 0; nt < 8; ++nt)
      o[nt] = __builtin_amdgcn_mfma_f32_16x16x32_bf16(pf, vf[nt], o[nt], 0, 0, 0);
  }

  // epilogue: normalize, round to 4 decimals, store fp32
#pragma unroll
  for (int nt = 0; nt < 8; ++nt)
#pragma unroll
    for (int i = 0; i < 4; ++i) {
      int qrow = qbase + g * 4 + i;
      float val = o[nt][i] / lrun[i];
      val = rintf(val * 1e4f) * 1e-4f;
      out[((size_t)b * Ss + qrow) * Aa + nt * 16 + c16] = val;
    }
}

// ---------------------------------------------------------------------------
extern "C" void kernel_launch(void* const* d_in, const int* in_sizes, int n_in,
                              void* d_out, int out_size, void* d_ws, size_t ws_size,
                              hipStream_t stream) {
  const float* X  = (const float*)d_in[0];
  const float* Wq = (const float*)d_in[1];
  const float* Wk = (const float*)d_in[2];
  const float* Wv = (const float*)d_in[3];
  float* out = (float*)d_out;

  unsigned char* ws = (unsigned char*)d_ws;
  unsigned short* Qb = (unsigned short*)(ws);                 // 16384*128 bf16 = 4 MB
  unsigned short* Kb = (unsigned short*)(ws + 4194304);       // 4 MB
  unsigned short* Vt = (unsigned short*)(ws + 8388608);       // [B][128][4096] = 4 MB
  unsigned short* Wt = (unsigned short*)(ws + 12582912);      // [3][128][1024] = 768 KB

  hipLaunchKernelGGL(wconv_kernel, dim3(512, 3), dim3(256), 0, stream, Wq, Wk, Wv, Wt);
  hipLaunchKernelGGL(qkv_kernel, dim3(128, 3), dim3(256), 0, stream, X, Wt, Qb, Kb, Vt);
  hipLaunchKernelGGL(attn_kernel, dim3(256, 4), dim3(64), 0, stream, Qb, Kb, Vt, out);
}

// Round 3
// 274.411 us; speedup vs baseline: 1.2266x; 1.1890x over previous
//
#include <hip/hip_runtime.h>
#include <hip/hip_bf16.h>
#include <math.h>

#define Bb 4
#define Ss 4096
#define Dd 1024
#define Aa 128

typedef __attribute__((ext_vector_type(4))) float f32x4;
typedef __attribute__((ext_vector_type(8))) short bf16x8;

static __device__ __forceinline__ unsigned short f2bf(float f) {
  union { float f; unsigned u; } v; v.f = f;
  unsigned r = v.u + 0x7fffu + ((v.u >> 16) & 1u);
  return (unsigned short)(r >> 16);
}

// ---------------------------------------------------------------------------
// Kernel 0: convert Wq/Wk/Wv (fp32 [D][A]) -> bf16 transposed Wt[w][n][k]
// ---------------------------------------------------------------------------
__global__ void wconv_kernel(const float* __restrict__ Wq, const float* __restrict__ Wk,
                             const float* __restrict__ Wv, unsigned short* __restrict__ Wt) {
  int w = blockIdx.y;
  const float* Wsrc = (w == 0) ? Wq : ((w == 1) ? Wk : Wv);
  int t = blockIdx.x * blockDim.x + threadIdx.x;
  if (t >= Dd * Aa) return;
  int k = t / Aa, n = t % Aa;
  Wt[(size_t)w * Aa * Dd + (size_t)n * Dd + k] = f2bf(Wsrc[t]);
}

// ---------------------------------------------------------------------------
// Kernel 1: QKV projection GEMM.  X [16384][1024] fp32  x  Wt[w] [128][1024] bf16
//   -> Qb (scaled by 1/sqrt(128)), Kb  as [16384][128] bf16
//   -> Vt as [B][128][4096] bf16 (transposed for the PV step)
// ---------------------------------------------------------------------------
__global__ __launch_bounds__(256) void qkv_kernel(const float* __restrict__ X,
    const unsigned short* __restrict__ Wt,
    unsigned short* __restrict__ Qb, unsigned short* __restrict__ Kb,
    unsigned short* __restrict__ Vt) {
  __shared__ unsigned short As[128][72];   // [m][k], +8 pad
  __shared__ unsigned short Bs[128][72];   // [n][k], +8 pad
  const int tid = threadIdx.x;
  const int lane = tid & 63;
  const int wid = tid >> 6;
  const int wr = wid >> 1, wc = wid & 1;
  const int g = lane >> 4, r16 = lane & 15;
  const int mblk = blockIdx.x;
  const int w = blockIdx.y;
  const unsigned short* Wsrc = Wt + (size_t)w * Aa * Dd;

  f32x4 acc[4][4];
  const f32x4 fz = {0.f, 0.f, 0.f, 0.f};
#pragma unroll
  for (int mi = 0; mi < 4; ++mi)
#pragma unroll
    for (int nj = 0; nj < 4; ++nj) acc[mi][nj] = fz;

  for (int kb = 0; kb < Dd; kb += 64) {
#pragma unroll
    for (int i = 0; i < 8; ++i) {
      int linear = tid + i * 256;
      int r = linear >> 4;
      int c = (linear & 15) << 2;
      const float4 v = *reinterpret_cast<const float4*>(
          &X[(size_t)(mblk * 128 + r) * Dd + kb + c]);
      ushort4 u;
      u.x = f2bf(v.x); u.y = f2bf(v.y); u.z = f2bf(v.z); u.w = f2bf(v.w);
      *reinterpret_cast<ushort4*>(&As[r][c]) = u;
    }
#pragma unroll
    for (int i = 0; i < 4; ++i) {
      int linear = tid + i * 256;
      int n = linear >> 3;
      int c = (linear & 7) << 3;
      *reinterpret_cast<int4*>(&Bs[n][c]) =
          *reinterpret_cast<const int4*>(&Wsrc[(size_t)n * Dd + kb + c]);
    }
    __syncthreads();
#pragma unroll
    for (int ks = 0; ks < 2; ++ks) {
      bf16x8 a[4], b[4];
#pragma unroll
      for (int mi = 0; mi < 4; ++mi)
        a[mi] = *reinterpret_cast<const bf16x8*>(&As[wr * 64 + mi * 16 + r16][ks * 32 + g * 8]);
#pragma unroll
      for (int nj = 0; nj < 4; ++nj)
        b[nj] = *reinterpret_cast<const bf16x8*>(&Bs[wc * 64 + nj * 16 + r16][ks * 32 + g * 8]);
#pragma unroll
      for (int mi = 0; mi < 4; ++mi)
#pragma unroll
        for (int nj = 0; nj < 4; ++nj)
          acc[mi][nj] = __builtin_amdgcn_mfma_f32_16x16x32_bf16(a[mi], b[nj], acc[mi][nj], 0, 0, 0);
    }
    __syncthreads();
  }

  const float qscale = 0.08838834764831845f;  // 1/sqrt(128)
#pragma unroll
  for (int mi = 0; mi < 4; ++mi) {
#pragma unroll
    for (int nj = 0; nj < 4; ++nj) {
#pragma unroll
      for (int i = 0; i < 4; ++i) {
        int m = wr * 64 + mi * 16 + g * 4 + i;
        int n = wc * 64 + nj * 16 + r16;
        size_t grow = (size_t)mblk * 128 + m;
        float val = acc[mi][nj][i];
        if (w == 0) {
          Qb[grow * Aa + n] = f2bf(val * qscale);
        } else if (w == 1) {
          Kb[grow * Aa + n] = f2bf(val);
        } else {
          size_t bb = grow >> 12;
          size_t s = grow & 4095;
          Vt[(bb * Aa + n) * Ss + s] = f2bf(val);
        }
      }
    }
  }
}

// ---------------------------------------------------------------------------
// Kernel 2: causal flash attention, SPLIT-KV x4.
// Block = 256 threads = 4 waves; block owns ONE 16-row q-tile; wave w handles
// kv-tile range [w*nkv/4, (w+1)*nkv/4). Partials (m,l,O) merged in LDS.
// 1024 blocks x 4 waves = 4096 waves = 4 waves/SIMD (all co-resident).
// ---------------------------------------------------------------------------
__global__ __launch_bounds__(256, 4) void attn_kernel(const unsigned short* __restrict__ Qb,
    const unsigned short* __restrict__ Kb, const unsigned short* __restrict__ Vt,
    float* __restrict__ out) {
  __shared__ float Osh[4][16][130];          // partial O, stride 130 -> 2-way (free)
  __shared__ float Msh[4][16];
  __shared__ float Lsh[4][16];
  __shared__ unsigned short Ps[4][16][40];   // per-wave P transpose buffer
  const int tid = threadIdx.x;
  const int lane = tid & 63;
  const int wid = tid >> 6;
  const int g = lane >> 4, c16 = lane & 15;
  const int bx = blockIdx.x;
  const int t = (bx & 1) ? (bx >> 1) : (255 - (bx >> 1));  // pair long+short
  const int b = blockIdx.y;
  const int qbase = t * 16;

  const int nkv = (qbase + 47) >> 5;         // tiles covering kv <= qbase+15
  const int itS = (wid * nkv) >> 2;
  const int itE = ((wid + 1) * nkv) >> 2;

  // Q fragments: A-operand, row=lane&15, k=8*(lane>>4)+i (pre-scaled by 1/sqrt(A))
  const unsigned short* Qp = Qb + ((size_t)b * Ss + qbase) * Aa;
  bf16x8 qf[4];
#pragma unroll
  for (int kk = 0; kk < 4; ++kk)
    qf[kk] = *reinterpret_cast<const bf16x8*>(&Qp[(size_t)c16 * Aa + kk * 32 + g * 8]);

  const unsigned short* Kbase = Kb + (size_t)b * Ss * Aa;
  const unsigned short* Vbase = Vt + (size_t)b * Aa * Ss;

  const f32x4 fz = {0.f, 0.f, 0.f, 0.f};
  f32x4 o[8];
#pragma unroll
  for (int nt = 0; nt < 8; ++nt) o[nt] = fz;
  float mrun[4], lrun[4];
#pragma unroll
  for (int i = 0; i < 4; ++i) { mrun[i] = -INFINITY; lrun[i] = 0.f; }

#pragma unroll 2
  for (int it = itS; it < itE; ++it) {
    const int kv0 = it * 32;
    bf16x8 kf[2][4];
#pragma unroll
    for (int nt = 0; nt < 2; ++nt)
#pragma unroll
      for (int kk = 0; kk < 4; ++kk)
        kf[nt][kk] = *reinterpret_cast<const bf16x8*>(
            &Kbase[(size_t)(kv0 + nt * 16 + c16) * Aa + kk * 32 + g * 8]);
    bf16x8 vf[8];
#pragma unroll
    for (int nt = 0; nt < 8; ++nt)
      vf[nt] = *reinterpret_cast<const bf16x8*>(
          &Vbase[(size_t)(nt * 16 + c16) * Ss + kv0 + g * 8]);

    f32x4 s0 = fz, s1 = fz;
#pragma unroll
    for (int kk = 0; kk < 4; ++kk)
      s0 = __builtin_amdgcn_mfma_f32_16x16x32_bf16(qf[kk], kf[0][kk], s0, 0, 0, 0);
#pragma unroll
    for (int kk = 0; kk < 4; ++kk)
      s1 = __builtin_amdgcn_mfma_f32_16x16x32_bf16(qf[kk], kf[1][kk], s1, 0, 0, 0);

    const bool need_mask = (kv0 + 31 > qbase);   // wave-uniform
    float e0[4], e1[4], sc[4];
#pragma unroll
    for (int i = 0; i < 4; ++i) {
      float v0 = s0[i], v1 = s1[i];
      if (need_mask) {
        int qrow = qbase + g * 4 + i;
        if (kv0 + c16 > qrow) v0 = -INFINITY;
        if (kv0 + 16 + c16 > qrow) v1 = -INFINITY;
      }
      float pm = fmaxf(v0, v1);
#pragma unroll
      for (int msk = 1; msk <= 8; msk <<= 1)
        pm = fmaxf(pm, __shfl_xor(pm, msk));
      float mnew = fmaxf(mrun[i], pm);
      float p0 = __expf(v0 - mnew);
      float p1 = __expf(v1 - mnew);
      sc[i] = __expf(mrun[i] - mnew);
      float rs = p0 + p1;
#pragma unroll
      for (int msk = 1; msk <= 8; msk <<= 1)
        rs += __shfl_xor(rs, msk);
      lrun[i] = lrun[i] * sc[i] + rs;
      mrun[i] = mnew;
      e0[i] = p0; e1[i] = p1;
    }
#pragma unroll
    for (int nt = 0; nt < 8; ++nt)
#pragma unroll
      for (int i = 0; i < 4; ++i) o[nt][i] *= sc[i];

    // P -> LDS transpose (wave-local; same-wave DS ordering, no barrier)
#pragma unroll
    for (int i = 0; i < 4; ++i) {
      Ps[wid][g * 4 + i][c16] = f2bf(e0[i]);
      Ps[wid][g * 4 + i][16 + c16] = f2bf(e1[i]);
    }
    bf16x8 pf = *reinterpret_cast<const bf16x8*>(&Ps[wid][c16][g * 8]);
#pragma unroll
    for (int nt = 0; nt < 8; ++nt)
      o[nt] = __builtin_amdgcn_mfma_f32_16x16x32_bf16(pf, vf[nt], o[nt], 0, 0, 0);
  }

  // write partials to LDS
#pragma unroll
  for (int nt = 0; nt < 8; ++nt)
#pragma unroll
    for (int i = 0; i < 4; ++i)
      Osh[wid][g * 4 + i][nt * 16 + c16] = o[nt][i];
  if (c16 == 0) {
#pragma unroll
    for (int i = 0; i < 4; ++i) {
      Msh[wid][g * 4 + i] = mrun[i];
      Lsh[wid][g * 4 + i] = lrun[i];
    }
  }
  __syncthreads();

  // combine: all 256 threads; thread -> row r = tid>>4, cols (tid&15)+16j
  const int r = tid >> 4;
  const int cb = tid & 15;
  float mf = -INFINITY;
#pragma unroll
  for (int w = 0; w < 4; ++w) mf = fmaxf(mf, Msh[w][r]);
  float lf = 0.f, sw[4];
#pragma unroll
  for (int w = 0; w < 4; ++w) {
    sw[w] = __expf(Msh[w][r] - mf);
    lf += Lsh[w][r] * sw[w];
  }
  const float inv = 1.0f / lf;
  const int qrow = qbase + r;
#pragma unroll
  for (int j = 0; j < 8; ++j) {
    int c = cb + 16 * j;
    float acc = 0.f;
#pragma unroll
    for (int w = 0; w < 4; ++w) acc += sw[w] * Osh[w][r][c];
    float val = acc * inv;
    val = rintf(val * 1e4f) * 1e-4f;
    out[((size_t)b * Ss + qrow) * Aa + c] = val;
  }
}

// ---------------------------------------------------------------------------
extern "C" void kernel_launch(void* const* d_in, const int* in_sizes, int n_in,
                              void* d_out, int out_size, void* d_ws, size_t ws_size,
                              hipStream_t stream) {
  const float* X  = (const float*)d_in[0];
  const float* Wq = (const float*)d_in[1];
  const float* Wk = (const float*)d_in[2];
  const float* Wv = (const float*)d_in[3];
  float* out = (float*)d_out;

  unsigned char* ws = (unsigned char*)d_ws;
  unsigned short* Qb = (unsigned short*)(ws);                 // 4 MB
  unsigned short* Kb = (unsigned short*)(ws + 4194304);       // 4 MB
  unsigned short* Vt = (unsigned short*)(ws + 8388608);       // 4 MB
  unsigned short* Wt = (unsigned short*)(ws + 12582912);      // 768 KB

  hipLaunchKernelGGL(wconv_kernel, dim3(512, 3), dim3(256), 0, stream, Wq, Wk, Wv, Wt);
  hipLaunchKernelGGL(qkv_kernel, dim3(128, 3), dim3(256), 0, stream, X, Wt, Qb, Kb, Vt);
  hipLaunchKernelGGL(attn_kernel, dim3(256, 4), dim3(256), 0, stream, Qb, Kb, Vt, out);
}